// Round 9
// baseline (438.948 us; speedup 1.0000x reference)
//
#include <hip/hip_runtime.h>
#include <hip/hip_bf16.h>
#include <stdint.h>

#define NN 50000     // nodes
#define NE 640000    // edges
#define NR 8         // relations
#define NK (NR * NN) // 400000 (rel,dst) keys
#define NB2 ((NK + 1023) / 1024)   // 391 scan blocks

typedef short bf16x8 __attribute__((ext_vector_type(8)));
typedef float f32x4  __attribute__((ext_vector_type(4)));

__device__ __forceinline__ unsigned short f2bf(float f) {
    union { float f; unsigned u; } v; v.f = f;
    unsigned r = v.u + 0x7FFF + ((v.u >> 16) & 1);
    return (unsigned short)(r >> 16);
}

// ---------------- CSR build over key = rel*NN + dst ----------------
__global__ void hist2_kernel(const int* __restrict__ dst, const int* __restrict__ et,
                             int* __restrict__ counts) {
    int e = blockIdx.x * 256 + threadIdx.x;
    if (e < NE) atomicAdd(&counts[et[e] * NN + dst[e]], 1);
}

__global__ __launch_bounds__(1024) void blocksum_kernel(const int* __restrict__ counts,
                                                        int* __restrict__ bsum, int n) {
    __shared__ int ws[16];
    int i = blockIdx.x * 1024 + threadIdx.x;
    int v = (i < n) ? counts[i] : 0;
    #pragma unroll
    for (int d = 32; d > 0; d >>= 1) v += __shfl_down(v, d, 64);
    int wid = threadIdx.x >> 6, lane = threadIdx.x & 63;
    if (lane == 0) ws[wid] = v;
    __syncthreads();
    if (threadIdx.x < 16) {
        int s = ws[threadIdx.x];
        #pragma unroll
        for (int d = 8; d > 0; d >>= 1) s += __shfl_down(s, d, 16);
        if (threadIdx.x == 0) bsum[blockIdx.x] = s;
    }
}

__global__ __launch_bounds__(512) void scanbase_kernel(const int* __restrict__ bsum,
                                                       int* __restrict__ base,
                                                       int* __restrict__ total, int nb) {
    __shared__ int ws[8];
    int t = threadIdx.x, lane = t & 63, wid = t >> 6;
    int v = (t < nb) ? bsum[t] : 0;
    int incl = v;
    #pragma unroll
    for (int d = 1; d < 64; d <<= 1) {
        int nv = __shfl_up(incl, d, 64);
        if (lane >= d) incl += nv;
    }
    if (lane == 63) ws[wid] = incl;
    __syncthreads();
    if (t < 8) {
        int s = ws[t], si = s;
        #pragma unroll
        for (int d = 1; d < 8; d <<= 1) {
            int nv = __shfl_up(si, d, 64);
            if (t >= d) si += nv;
        }
        ws[t] = si - s;   // exclusive wave base
    }
    __syncthreads();
    int excl = ws[wid] + incl - v;
    if (t < nb) base[t] = excl;
    if (t == 511) total[0] = ws[7] + incl;
}

__global__ __launch_bounds__(1024) void scanlocal_kernel(const int* __restrict__ counts,
                                                         const int* __restrict__ base,
                                                         int* __restrict__ offsets,
                                                         int* __restrict__ cursor, int n) {
    __shared__ int ws[16];
    __shared__ int wbase[16];
    int t = threadIdx.x;
    int i = blockIdx.x * 1024 + t;
    int v = (i < n) ? counts[i] : 0;
    int lane = t & 63, wid = t >> 6;
    int incl = v;
    #pragma unroll
    for (int d = 1; d < 64; d <<= 1) {
        int nv = __shfl_up(incl, d, 64);
        if (lane >= d) incl += nv;
    }
    if (lane == 63) ws[wid] = incl;
    __syncthreads();
    if (t < 16) {
        int s = ws[t], si = s;
        #pragma unroll
        for (int d = 1; d < 16; d <<= 1) {
            int nv = __shfl_up(si, d, 16);
            if (t >= d) si += nv;
        }
        wbase[t] = si - s;
    }
    __syncthreads();
    if (i < n) {
        int excl = base[blockIdx.x] + wbase[wid] + incl - v;
        offsets[i] = excl;
        cursor[i]  = excl;
    }
}

__global__ void fill2_kernel(const int* __restrict__ src, const int* __restrict__ dst,
                             const int* __restrict__ et, int* __restrict__ cursor,
                             int* __restrict__ esrc) {
    int e = blockIdx.x * 256 + threadIdx.x;
    if (e < NE) {
        int pos = atomicAdd(&cursor[et[e] * NN + dst[e]], 1);
        esrc[pos] = src[e];
    }
}

// ---------------- dtype prep ----------------
__global__ void cvt_bf16_kernel(const float* __restrict__ in, unsigned short* __restrict__ outp,
                                int n8) {
    int i = blockIdx.x * 256 + threadIdx.x;
    if (i >= n8) return;
    const float4* pp = (const float4*)in + (size_t)i * 2;
    float4 a = pp[0], b = pp[1];
    uint4 o;
    o.x = (unsigned)f2bf(a.x) | ((unsigned)f2bf(a.y) << 16);
    o.y = (unsigned)f2bf(a.z) | ((unsigned)f2bf(a.w) << 16);
    o.z = (unsigned)f2bf(b.x) | ((unsigned)f2bf(b.y) << 16);
    o.w = (unsigned)f2bf(b.z) | ((unsigned)f2bf(b.w) << 16);
    ((uint4*)outp)[i] = o;
}

// WT[(r*DOUTV+o)][k] bf16; r==8 -> Wself
template<int DOUTV>
__global__ void prepW_kernel(const float* __restrict__ W, const float* __restrict__ Wself,
                             unsigned short* __restrict__ WT) {
    int idx = blockIdx.x * 256 + threadIdx.x;
    if (idx >= 9 * DOUTV * 128) return;
    int k = idx & 127;
    int c = idx >> 7;
    int r = c / DOUTV;
    int o = c - r * DOUTV;
    float v = (r < 8) ? W[((size_t)r * 128 + k) * DOUTV + o]
                      : Wself[(size_t)k * DOUTV + o];
    WT[idx] = f2bf(v);
}

// ---------------- per-(rel,dst) segment aggregation ----------------
// Wave per key k = r*NN+dst: agg[k][:] = sum_{e in seg(k)} A[esrc[e]][:].
// Lane owns cols 2l,2l+1 (one uint of the 256B row). fp32 accumulate, one bf16
// round on store. 400k independent waves, no barriers, full 256B-row writes.
__global__ __launch_bounds__(256) void agg_seg(
        const unsigned short* __restrict__ A,     // [NN][128] bf16
        const int* __restrict__ off2,             // [NK+1]
        const int* __restrict__ esrc,             // [NE] sorted by (rel,dst)
        unsigned short* __restrict__ agg) {       // [NK][128] bf16
    int wv = threadIdx.x >> 6, l = threadIdx.x & 63;
    int k = blockIdx.x * 4 + wv;                  // NK % 4 == 0
    int e0 = off2[k], e1 = off2[k + 1];
    const unsigned* R = (const unsigned*)A;
    float ax = 0.f, ay = 0.f;
    int j = e0;
    for (; j + 4 <= e1; j += 4) {
        int s0 = esrc[j], s1 = esrc[j + 1], s2 = esrc[j + 2], s3 = esrc[j + 3];
        unsigned p0 = R[((size_t)s0 << 6) + l];
        unsigned p1 = R[((size_t)s1 << 6) + l];
        unsigned p2 = R[((size_t)s2 << 6) + l];
        unsigned p3 = R[((size_t)s3 << 6) + l];
        ax += __uint_as_float(p0 << 16) + __uint_as_float(p1 << 16)
            + __uint_as_float(p2 << 16) + __uint_as_float(p3 << 16);
        ay += __uint_as_float(p0 & 0xffff0000u) + __uint_as_float(p1 & 0xffff0000u)
            + __uint_as_float(p2 & 0xffff0000u) + __uint_as_float(p3 & 0xffff0000u);
    }
    for (; j < e1; ++j) {
        unsigned p = R[((size_t)esrc[j] << 6) + l];
        ax += __uint_as_float(p << 16);
        ay += __uint_as_float(p & 0xffff0000u);
    }
    ((unsigned*)agg)[((size_t)k << 6) + l] = (unsigned)f2bf(ax) | ((unsigned)f2bf(ay) << 16);
}

// ---------------- summed MFMA GEMM ----------------
// C[m][n] = sum_{r=0..7} agg_r[m]@WT_r[n] + feat[m]@WT_8[n] + bias[n], K=9*128.
// BM=64 (782 blocks, ~3/CU). 9 stages, each staging As (16KB) + Ws (NOUT*256B)
// into XOR-swizzled LDS, all-LDS K-loop (round-3-validated pattern).
// 4 waves in 2x2: wave tile 32m x (NOUT/2)n. Epilogue: LDS repack -> full-row
// coalesced stores (256B lines, no partial-line write allocation).
template<int NOUT, bool RELU, bool OUTBF16>
__global__ __launch_bounds__(256) void gemm_sum(
        const unsigned short* __restrict__ agg,   // [NR*NN][128] bf16
        const unsigned short* __restrict__ feat,  // [M][128] bf16 (self stage)
        const unsigned short* __restrict__ WT,    // [9*NOUT][128] bf16
        const float* __restrict__ bias,           // [NOUT]
        void* __restrict__ outp, int M) {
    constexpr int NJ = NOUT / 32;                 // n-tiles per wave
    __shared__ __align__(16) unsigned char smem[16384 + NOUT * 256];
    unsigned short* As = (unsigned short*)smem;            // 64 x 256B swizzled
    unsigned short* Ws = (unsigned short*)(smem + 16384);  // NOUT x 256B swizzled

    const int t = threadIdx.x;
    const int n0 = blockIdx.x * 64;
    const int lane = t & 63;
    const int w = t >> 6;
    const int r15 = lane & 15;
    const int q = lane >> 4;
    const int wm = (w & 1) * 32;
    const int wn = (w >> 1) * (NOUT / 2);

    f32x4 acc[2][NJ] = {};

    for (int r = 0; r < 9; ++r) {
        const unsigned short* Ab = (r < 8) ? agg + (((size_t)r * NN) << 7) : feat;
        __syncthreads();   // prior stage's frag reads done
        // stage A tile: 1024 chunks (64 rows x 16), 4/thread
        #pragma unroll
        for (int i = 0; i < 4; i++) {
            int g = t + i * 256;
            int row = g >> 4, c = g & 15;
            int m = n0 + row;
            uint4 v = make_uint4(0, 0, 0, 0);
            if (m < M) v = *(const uint4*)(Ab + ((size_t)m << 7) + c * 8);
            *(uint4*)((char*)As + row * 256 + ((c ^ (row & 15)) << 4)) = v;
        }
        // stage B tile: NOUT x 16 chunks
        #pragma unroll
        for (int i = 0; i < NOUT / 16; i++) {
            int g = t + i * 256;
            int row = g >> 4, c = g & 15;
            uint4 v = *(const uint4*)(WT + ((size_t)(r * NOUT + row) << 7) + c * 8);
            *(uint4*)((char*)Ws + row * 256 + ((c ^ (row & 15)) << 4)) = v;
        }
        __syncthreads();
        #pragma unroll
        for (int ks = 0; ks < 4; ks++) {
            int c = (ks * 4 + q) ^ r15;
            bf16x8 af[2];
            #pragma unroll
            for (int i = 0; i < 2; i++)
                af[i] = *(const bf16x8*)((const char*)As + (wm + i * 16 + r15) * 256 + (c << 4));
            #pragma unroll
            for (int j = 0; j < NJ; j++) {
                bf16x8 bf = *(const bf16x8*)((const char*)Ws + (wn + j * 16 + r15) * 256 + (c << 4));
                #pragma unroll
                for (int i = 0; i < 2; i++)
                    acc[i][j] = __builtin_amdgcn_mfma_f32_16x16x32_bf16(af[i], bf, acc[i][j], 0, 0, 0);
            }
        }
    }
    __syncthreads();   // all LDS reads done; reuse smem for C repack

    // ---- epilogue: bias (+ReLU), repack in LDS, coalesced full-row stores ----
    if (OUTBF16) {
        unsigned short* Cs = (unsigned short*)smem;   // stride 136 shorts (272B rows)
        #pragma unroll
        for (int j = 0; j < NJ; j++) {
            int n = wn + j * 16 + r15;
            float bv = bias[n];
            #pragma unroll
            for (int i = 0; i < 2; i++) {
                #pragma unroll
                for (int reg = 0; reg < 4; reg++) {
                    float v = acc[i][j][reg] + bv;
                    if (RELU) v = fmaxf(v, 0.f);
                    Cs[(wm + i * 16 + q * 4 + reg) * 136 + n] = f2bf(v);
                }
            }
        }
        __syncthreads();
        unsigned short* O = (unsigned short*)outp;
        #pragma unroll
        for (int i = 0; i < (NOUT == 128 ? 4 : 2); i++) {
            int g = t + i * 256;                      // 64 rows x (NOUT/8) chunks
            int row = g / (NOUT / 8), c = g % (NOUT / 8);
            int m = n0 + row;
            if (m < M)
                *(uint4*)(O + (size_t)m * NOUT + c * 8) = *(const uint4*)(Cs + row * 136 + c * 8);
        }
    } else {
        float* Cs = (float*)smem;                     // stride 68 floats (272B rows)
        #pragma unroll
        for (int j = 0; j < NJ; j++) {
            int n = wn + j * 16 + r15;
            float bv = bias[n];
            #pragma unroll
            for (int i = 0; i < 2; i++) {
                #pragma unroll
                for (int reg = 0; reg < 4; reg++) {
                    float v = acc[i][j][reg] + bv;
                    if (RELU) v = fmaxf(v, 0.f);
                    Cs[(wm + i * 16 + q * 4 + reg) * 68 + n] = v;
                }
            }
        }
        __syncthreads();
        float* O = (float*)outp;
        #pragma unroll
        for (int i = 0; i < NOUT / 16; i++) {
            int g = t + i * 256;                      // 64 rows x (NOUT/4) chunks
            int row = g / (NOUT / 4), c = g % (NOUT / 4);
            int m = n0 + row;
            if (m < M)
                *(uint4*)(O + (size_t)m * NOUT + c * 4) = *(const uint4*)(Cs + row * 68 + c * 4);
        }
    }
}

extern "C" void kernel_launch(void* const* d_in, const int* in_sizes, int n_in,
                              void* d_out, int out_size, void* d_ws, size_t ws_size,
                              hipStream_t stream) {
    const float* X   = (const float*)d_in[0];
    const int*   src = (const int*)d_in[1];
    const int*   dst = (const int*)d_in[2];
    const int*   et  = (const int*)d_in[3];
    const float* W1  = (const float*)d_in[4];
    const float* W1s = (const float*)d_in[5];
    const float* b1  = (const float*)d_in[6];
    const float* W2  = (const float*)d_in[7];
    const float* W2s = (const float*)d_in[8];
    const float* b2  = (const float*)d_in[9];
    float* out = (float*)d_out;

    // workspace carve (~136 MB)
    char* p = (char*)d_ws;
    unsigned short* agg = (unsigned short*)p; p += (size_t)NK * 128 * 2;       // 102.4 MB (both layers)
    unsigned short* Xbf = (unsigned short*)p; p += (size_t)NN * 128 * 2;       // 12.8 MB
    unsigned short* hbf = (unsigned short*)p; p += (size_t)NN * 128 * 2;       // 12.8 MB
    unsigned short* W1T = (unsigned short*)p; p += (size_t)9 * 128 * 128 * 2;  // 288 KB
    unsigned short* W2T = (unsigned short*)p; p += (size_t)9 * 64 * 128 * 2;   // 144 KB
    int* counts2 = (int*)p; p += (size_t)NK * 4;                               // 1.6 MB
    int* off2    = (int*)p; p += (size_t)(NK + 4) * 4;                         // 1.6 MB
    int* cursor2 = (int*)p; p += (size_t)NK * 4;                               // 1.6 MB
    int* esrc    = (int*)p; p += (size_t)NE * 4;                               // 2.56 MB
    int* bsum    = (int*)p; p += 512 * 4;
    int* bbase   = (int*)p; p += 512 * 4;

    // (rel,dst)-sorted CSR (static graph, shared by both layers)
    hipMemsetAsync(counts2, 0, (size_t)NK * sizeof(int), stream);
    hist2_kernel<<<(NE + 255) / 256, 256, 0, stream>>>(dst, et, counts2);
    blocksum_kernel<<<NB2, 1024, 0, stream>>>(counts2, bsum, NK);
    scanbase_kernel<<<1, 512, 0, stream>>>(bsum, bbase, &off2[NK], NB2);
    scanlocal_kernel<<<NB2, 1024, 0, stream>>>(counts2, bbase, off2, cursor2, NK);
    fill2_kernel<<<(NE + 255) / 256, 256, 0, stream>>>(src, dst, et, cursor2, esrc);

    // dtype prep
    cvt_bf16_kernel<<<(NN * 128 / 8 + 255) / 256, 256, 0, stream>>>(X, Xbf, NN * 128 / 8);
    prepW_kernel<128><<<(9 * 128 * 128 + 255) / 256, 256, 0, stream>>>(W1, W1s, W1T);
    prepW_kernel<64><<<(9 * 64 * 128 + 255) / 256, 256, 0, stream>>>(W2, W2s, W2T);

    const int gblk = (NN + 63) / 64;   // 782

    // Layer 1: agg = segsum(Xbf); h = relu(sum_r agg_r@W1_r + Xbf@W1s + b1) -> bf16
    agg_seg<<<NK / 4, 256, 0, stream>>>(Xbf, off2, esrc, agg);
    gemm_sum<128, true, true><<<gblk, 256, 0, stream>>>(agg, Xbf, W1T, b1, hbf, NN);

    // Layer 2: agg = segsum(hbf); out = sum_r agg_r@W2_r + hbf@W2s + b2 (fp32)
    agg_seg<<<NK / 4, 256, 0, stream>>>(hbf, off2, esrc, agg);
    gemm_sum<64, false, false><<<gblk, 256, 0, stream>>>(agg, hbf, W2T, b2, out, NN);
}

// Round 10
// 327.888 us; speedup vs baseline: 1.3387x; 1.3387x over previous
//
#include <hip/hip_runtime.h>
#include <hip/hip_bf16.h>
#include <stdint.h>

#define NN 50000     // nodes
#define NE 640000    // edges
#define NR 8         // relations
#define NK (NR * NN) // 400000 (rel,dst) keys
#define NB2 ((NK + 1023) / 1024)   // 391 scan blocks

typedef short bf16x8 __attribute__((ext_vector_type(8)));
typedef float f32x4  __attribute__((ext_vector_type(4)));

__device__ __forceinline__ unsigned short f2bf(float f) {
    union { float f; unsigned u; } v; v.f = f;
    unsigned r = v.u + 0x7FFF + ((v.u >> 16) & 1);
    return (unsigned short)(r >> 16);
}

// ---------------- fused prep: hist2 + cvt_bf16 + prepW1 + prepW2 ----------------
// blockIdx ranges: [0,2500) hist; [2500,5625) cvt; [5625,6201) prepW<128>; [6201,6489) prepW<64>.
__global__ __launch_bounds__(256) void prep_all(
        const int* __restrict__ dst, const int* __restrict__ et, int* __restrict__ counts,
        const float* __restrict__ X, unsigned short* __restrict__ Xbf,
        const float* __restrict__ W1, const float* __restrict__ W1s, unsigned short* __restrict__ W1T,
        const float* __restrict__ W2, const float* __restrict__ W2s, unsigned short* __restrict__ W2T) {
    int b = blockIdx.x, t = threadIdx.x;
    if (b < 2500) {                               // histogram over (rel,dst) keys
        int e = b * 256 + t;
        atomicAdd(&counts[et[e] * NN + dst[e]], 1);
    } else if (b < 5625) {                        // X fp32 -> bf16, 8 elems/thread
        int i = (b - 2500) * 256 + t;             // 800000 = NN*128/8
        const float4* pp = (const float4*)X + (size_t)i * 2;
        float4 a = pp[0], c = pp[1];
        uint4 o;
        o.x = (unsigned)f2bf(a.x) | ((unsigned)f2bf(a.y) << 16);
        o.y = (unsigned)f2bf(a.z) | ((unsigned)f2bf(a.w) << 16);
        o.z = (unsigned)f2bf(c.x) | ((unsigned)f2bf(c.y) << 16);
        o.w = (unsigned)f2bf(c.z) | ((unsigned)f2bf(c.w) << 16);
        ((uint4*)Xbf)[i] = o;
    } else if (b < 6201) {                        // W1T[(r*128+o)][k]; r==8 -> W1s
        int idx = (b - 5625) * 256 + t;           // 147456 = 9*128*128
        int k = idx & 127, c = idx >> 7;
        int r = c >> 7, o = c & 127;
        float v = (r < 8) ? W1[((size_t)r * 128 + k) * 128 + o]
                          : W1s[(size_t)k * 128 + o];
        W1T[idx] = f2bf(v);
    } else {                                      // W2T[(r*64+o)][k]; r==8 -> W2s
        int idx = (b - 6201) * 256 + t;           // 73728 = 9*64*128
        int k = idx & 127, c = idx >> 7;
        int r = c / 64, o = c - r * 64;
        float v = (r < 8) ? W2[((size_t)r * 128 + k) * 64 + o]
                          : W2s[(size_t)k * 64 + o];
        W2T[idx] = f2bf(v);
    }
}

// ---------------- scan chain over counts (NK keys) ----------------
__global__ __launch_bounds__(1024) void blocksum_kernel(const int* __restrict__ counts,
                                                        int* __restrict__ bsum, int n) {
    __shared__ int ws[16];
    int i = blockIdx.x * 1024 + threadIdx.x;
    int v = (i < n) ? counts[i] : 0;
    #pragma unroll
    for (int d = 32; d > 0; d >>= 1) v += __shfl_down(v, d, 64);
    int wid = threadIdx.x >> 6, lane = threadIdx.x & 63;
    if (lane == 0) ws[wid] = v;
    __syncthreads();
    if (threadIdx.x < 16) {
        int s = ws[threadIdx.x];
        #pragma unroll
        for (int d = 8; d > 0; d >>= 1) s += __shfl_down(s, d, 16);
        if (threadIdx.x == 0) bsum[blockIdx.x] = s;
    }
}

__global__ __launch_bounds__(512) void scanbase_kernel(const int* __restrict__ bsum,
                                                       int* __restrict__ base,
                                                       int* __restrict__ total, int nb) {
    __shared__ int ws[8];
    int t = threadIdx.x, lane = t & 63, wid = t >> 6;
    int v = (t < nb) ? bsum[t] : 0;
    int incl = v;
    #pragma unroll
    for (int d = 1; d < 64; d <<= 1) {
        int nv = __shfl_up(incl, d, 64);
        if (lane >= d) incl += nv;
    }
    if (lane == 63) ws[wid] = incl;
    __syncthreads();
    if (t < 8) {
        int s = ws[t], si = s;
        #pragma unroll
        for (int d = 1; d < 8; d <<= 1) {
            int nv = __shfl_up(si, d, 64);
            if (t >= d) si += nv;
        }
        ws[t] = si - s;   // exclusive wave base
    }
    __syncthreads();
    int excl = ws[wid] + incl - v;
    if (t < nb) base[t] = excl;
    if (t == 511) total[0] = ws[7] + incl;
}

__global__ __launch_bounds__(1024) void scanlocal_kernel(const int* __restrict__ counts,
                                                         const int* __restrict__ base,
                                                         int* __restrict__ offsets,
                                                         int* __restrict__ cursor, int n) {
    __shared__ int ws[16];
    __shared__ int wbase[16];
    int t = threadIdx.x;
    int i = blockIdx.x * 1024 + t;
    int v = (i < n) ? counts[i] : 0;
    int lane = t & 63, wid = t >> 6;
    int incl = v;
    #pragma unroll
    for (int d = 1; d < 64; d <<= 1) {
        int nv = __shfl_up(incl, d, 64);
        if (lane >= d) incl += nv;
    }
    if (lane == 63) ws[wid] = incl;
    __syncthreads();
    if (t < 16) {
        int s = ws[t], si = s;
        #pragma unroll
        for (int d = 1; d < 16; d <<= 1) {
            int nv = __shfl_up(si, d, 16);
            if (t >= d) si += nv;
        }
        wbase[t] = si - s;
    }
    __syncthreads();
    if (i < n) {
        int excl = base[blockIdx.x] + wbase[wid] + incl - v;
        offsets[i] = excl;
        cursor[i]  = excl;
    }
}

__global__ void fill2_kernel(const int* __restrict__ src, const int* __restrict__ dst,
                             const int* __restrict__ et, int* __restrict__ cursor,
                             int* __restrict__ esrc) {
    int e = blockIdx.x * 256 + threadIdx.x;
    if (e < NE) {
        int pos = atomicAdd(&cursor[et[e] * NN + dst[e]], 1);
        esrc[pos] = src[e];
    }
}

// ---------------- Fused aggregate + transform layer ----------------
// Per block: 64 dst nodes, 256 threads. Edges sorted by (rel,dst): each (r,dst)
// segment is contiguous and uniquely owned -> ATOMIC-FREE aggregation.
// Thread t owns dst row (t>>2), column group (t&3): 32 cols accumulated in 32
// registers over its segment, gathered with a 4-EDGE software pipeline (4 esrc
// + 16 row dwordx4 independent loads in flight) to hide the ~1000-cyc
// esrc->row L2/L3 chain that bounded round 6 (81 us, all pipes <25%).
// MFMA-accumulates C[64][NOUT] += agg_r @ W[r]^T across r=0..7 plus self (idx 8).
template<int NOUT, bool RELU, bool OUTBF16>
__global__ __launch_bounds__(256) void fused_layer(
        const unsigned short* __restrict__ A,    // [M][128] bf16 node features
        const unsigned short* __restrict__ WT,   // [9*NOUT][128] bf16
        const float* __restrict__ bias,          // [NOUT]
        const int* __restrict__ off2,            // [NK+1]
        const int* __restrict__ esrc,            // [NE] src sorted by (rel,dst)
        void* __restrict__ outp, int M) {
    constexpr int CW = NOUT / 4;      // cols per wave (MFMA)
    constexpr int NJ = CW / 16;       // n-tiles per wave
    __shared__ unsigned short Asw[64 * 128];    // swizzled bf16 A-operand (16 KB)

    const int t = threadIdx.x;
    const int n0 = blockIdx.x * 64;
    const int bm = (M - n0 < 64) ? (M - n0) : 64;
    const int lane = t & 63;
    const int w = t >> 6;
    const int r15 = lane & 15;
    const int q = lane >> 4;

    const int key = t >> 2;          // local dst row 0..63
    const int sub = t & 3;           // col group: uints [sub*16, sub*16+16)
    const int kk = n0 + key;
    const bool kv = (kk < M);

    f32x4 acc[4][NJ] = {};

    auto do_mfma = [&](int rr) {
        #pragma unroll
        for (int ks = 0; ks < 4; ks++) {
            int c = (ks * 4 + q) ^ r15;
            bf16x8 af[4];
            #pragma unroll
            for (int i = 0; i < 4; i++)
                af[i] = *(const bf16x8*)((const char*)Asw + (i * 16 + r15) * 256 + (c << 4));
            #pragma unroll
            for (int j = 0; j < NJ; j++) {
                bf16x8 bf = *(const bf16x8*)(WT +
                    ((size_t)(rr * NOUT + w * CW + j * 16 + r15) << 7) + ks * 32 + q * 8);
                #pragma unroll
                for (int i = 0; i < 4; i++)
                    acc[i][j] = __builtin_amdgcn_mfma_f32_16x16x32_bf16(af[i], bf, acc[i][j], 0, 0, 0);
            }
        }
    };

    // prefetch relation-0 segment bounds
    int e0 = kv ? off2[kk] : 0;
    int e1 = kv ? off2[kk + 1] : 0;

    // ---- self pass (K-chunk index 8): Asw = own feature rows ----
    #pragma unroll
    for (int kc = 0; kc < 4; kc++) {
        int g = t + kc * 256;           // 1024 chunks = 64 rows x 16
        int row = g >> 4, c = g & 15;
        uint4 v = make_uint4(0, 0, 0, 0);
        if (row < bm) v = *(const uint4*)(A + ((size_t)(n0 + row) << 7) + c * 8);
        *(uint4*)((char*)Asw + row * 256 + ((c ^ (row & 15)) << 4)) = v;
    }
    __syncthreads();
    do_mfma(8);

    // ---- relation passes ----
    for (int r = 0; r < 8; r++) {
        // prefetch next relation's bounds (consumed next iteration)
        int e0n = 0, e1n = 0;
        if (r < 7 && kv) {
            e0n = off2[(r + 1) * NN + kk];
            e1n = off2[(r + 1) * NN + kk + 1];
        }

        // register-accumulate own segment, 4-edge pipelined
        float a[32];
        #pragma unroll
        for (int i = 0; i < 32; i++) a[i] = 0.f;

        const unsigned* base = (const unsigned*)A;
        for (int e = e0; e < e1; e += 4) {
            int rem = e1 - e;
            int i1 = (rem > 1) ? 1 : 0, i2 = (rem > 2) ? 2 : 0, i3 = (rem > 3) ? 3 : 0;
            int ss[4];
            ss[0] = esrc[e];
            ss[1] = esrc[e + i1];
            ss[2] = esrc[e + i2];
            ss[3] = esrc[e + i3];
            float wts[4];
            wts[0] = 1.f;
            wts[1] = i1 ? 1.f : 0.f;
            wts[2] = i2 ? 1.f : 0.f;
            wts[3] = i3 ? 1.f : 0.f;
            uint4 va[4][4];
            #pragma unroll
            for (int i = 0; i < 4; i++) {
                const uint4* rp = (const uint4*)(base + ((size_t)ss[i] << 6) + sub * 16);
                #pragma unroll
                for (int u = 0; u < 4; u++) va[i][u] = rp[u];
            }
            #pragma unroll
            for (int i = 0; i < 4; i++) {
                #pragma unroll
                for (int u = 0; u < 4; u++) {
                    unsigned uu[4] = {va[i][u].x, va[i][u].y, va[i][u].z, va[i][u].w};
                    #pragma unroll
                    for (int j = 0; j < 4; j++) {
                        a[u * 8 + j * 2 + 0] = fmaf(wts[i], __uint_as_float(uu[j] << 16), a[u * 8 + j * 2 + 0]);
                        a[u * 8 + j * 2 + 1] = fmaf(wts[i], __uint_as_float(uu[j] & 0xffff0000u), a[u * 8 + j * 2 + 1]);
                    }
                }
            }
        }
        __syncthreads();   // all waves done reading Asw from previous MFMA

        // pack to bf16 and write 4 swizzled 16B chunks (c = sub*4+c4)
        #pragma unroll
        for (int c4 = 0; c4 < 4; ++c4) {
            uint4 pv;
            pv.x = (unsigned)f2bf(a[c4 * 8 + 0]) | ((unsigned)f2bf(a[c4 * 8 + 1]) << 16);
            pv.y = (unsigned)f2bf(a[c4 * 8 + 2]) | ((unsigned)f2bf(a[c4 * 8 + 3]) << 16);
            pv.z = (unsigned)f2bf(a[c4 * 8 + 4]) | ((unsigned)f2bf(a[c4 * 8 + 5]) << 16);
            pv.w = (unsigned)f2bf(a[c4 * 8 + 6]) | ((unsigned)f2bf(a[c4 * 8 + 7]) << 16);
            int c = sub * 4 + c4;
            *(uint4*)((char*)Asw + key * 256 + ((c ^ (key & 15)) << 4)) = pv;
        }
        __syncthreads();

        do_mfma(r);
        e0 = e0n; e1 = e1n;
    }

    // ---- epilogue: + bias, optional ReLU, store ----
    #pragma unroll
    for (int j = 0; j < NJ; j++) {
        int col = w * CW + j * 16 + r15;
        float bv = bias[col];
        #pragma unroll
        for (int i = 0; i < 4; i++) {
            #pragma unroll
            for (int reg = 0; reg < 4; reg++) {
                int m = n0 + i * 16 + q * 4 + reg;
                if (m < M) {
                    float v = acc[i][j][reg] + bv;
                    if (RELU) v = fmaxf(v, 0.f);
                    if (OUTBF16)
                        ((unsigned short*)outp)[(size_t)m * NOUT + col] = f2bf(v);
                    else
                        ((float*)outp)[(size_t)m * NOUT + col] = v;
                }
            }
        }
    }
}

extern "C" void kernel_launch(void* const* d_in, const int* in_sizes, int n_in,
                              void* d_out, int out_size, void* d_ws, size_t ws_size,
                              hipStream_t stream) {
    const float* X   = (const float*)d_in[0];
    const int*   src = (const int*)d_in[1];
    const int*   dst = (const int*)d_in[2];
    const int*   et  = (const int*)d_in[3];
    const float* W1  = (const float*)d_in[4];
    const float* W1s = (const float*)d_in[5];
    const float* b1  = (const float*)d_in[6];
    const float* W2  = (const float*)d_in[7];
    const float* W2s = (const float*)d_in[8];
    const float* b2  = (const float*)d_in[9];
    float* out = (float*)d_out;

    // workspace carve (~34 MB)
    char* p = (char*)d_ws;
    unsigned short* Xbf = (unsigned short*)p; p += (size_t)NN * 128 * 2;       // 12.8 MB
    unsigned short* hbf = (unsigned short*)p; p += (size_t)NN * 128 * 2;       // 12.8 MB
    unsigned short* W1T = (unsigned short*)p; p += (size_t)9 * 128 * 128 * 2;  // 288 KB
    unsigned short* W2T = (unsigned short*)p; p += (size_t)9 * 64 * 128 * 2;   // 144 KB
    int* counts2 = (int*)p; p += (size_t)NK * 4;                               // 1.6 MB
    int* off2    = (int*)p; p += (size_t)(NK + 4) * 4;                         // 1.6 MB
    int* cursor2 = (int*)p; p += (size_t)NK * 4;                               // 1.6 MB
    int* esrc    = (int*)p; p += (size_t)NE * 4;                               // 2.56 MB
    int* bsum    = (int*)p; p += 512 * 4;
    int* bbase   = (int*)p; p += 512 * 4;

    // zero counts, then fused prep (hist + cvt + both weight transposes)
    hipMemsetAsync(counts2, 0, (size_t)NK * sizeof(int), stream);
    prep_all<<<6489, 256, 0, stream>>>(dst, et, counts2, X, Xbf,
                                       W1, W1s, W1T, W2, W2s, W2T);

    // (rel,dst)-sorted CSR
    blocksum_kernel<<<NB2, 1024, 0, stream>>>(counts2, bsum, NK);
    scanbase_kernel<<<1, 512, 0, stream>>>(bsum, bbase, &off2[NK], NB2);
    scanlocal_kernel<<<NB2, 1024, 0, stream>>>(counts2, bbase, off2, cursor2, NK);
    fill2_kernel<<<(NE + 255) / 256, 256, 0, stream>>>(src, dst, et, cursor2, esrc);

    const int nblk = (NN + 63) / 64;  // 782

    // Layer 1: h = relu(agg1 + X@W1s + b1), stored bf16
    fused_layer<128, true, true><<<nblk, 256, 0, stream>>>(
        Xbf, W1T, b1, off2, esrc, hbf, NN);
    // Layer 2: out = agg2 + h@W2s + b2, fp32
    fused_layer<64, false, false><<<nblk, 256, 0, stream>>>(
        hbf, W2T, b2, off2, esrc, out, NN);
}